// Round 4
// baseline (445.840 us; speedup 1.0000x reference)
//
#include <hip/hip_runtime.h>
#include <hip/hip_bf16.h>

// Lukasiewicz t-norm feature expansion, write-BW-bound (~365 MB out).
//   out[:, 0:16]    = x
//   out[:, 16:136]  = max(x[a]+x[b] - 1, 0)        (a,b)   lex combos of 16
//   out[:, 136:696] = max(x[a]+x[b]+x[c] - 2, 0)   (a,b,c) lex combos of 16
//
// R4: thread = row, combos are COMPILE-TIME (constexpr tables + full unroll)
//   -> zero loads per output, ~2-3 VALU each, pair-sums CSE'd by compiler.
// Coalesced stores via wave-private LDS transpose (ds_write_b128/ds_read_b128,
// stride 7 quads = conflict-free 8-phase). Only lgkmcnt fences
// (__threadfence_block) -- no __syncthreads, so stores never drain (vmcnt
// stays deep across chunks).
// R2/R3 (per-lane column table, 12 ds_read_b32 + ~48 VALU per quad) ~2.8 TB/s.

#define NCOLS 696
#define ROWS_PER_BLOCK 256
#define CHUNK_COLS 24
#define CHUNK_QUADS 6        // 24 cols / 4
#define NCHUNKS 29           // 29 * 24 = 696
#define LDS_STRIDE_Q 7       // 6 quads + 1 pad quad per lane-row

typedef float v4f __attribute__((ext_vector_type(4)));

struct Tabs { short a[NCOLS]; short b[NCOLS]; short c[NCOLS]; };

// itertools.combinations lexicographic order; b/c = -1 marks arity 1/2.
constexpr Tabs make_tabs() {
    Tabs t{};
    int k = 0;
    for (int a = 0; a < 16; ++a) { t.a[k] = (short)a; t.b[k] = -1; t.c[k] = -1; ++k; }
    for (int a = 0; a < 16; ++a)
        for (int b = a + 1; b < 16; ++b) { t.a[k] = (short)a; t.b[k] = (short)b; t.c[k] = -1; ++k; }
    for (int a = 0; a < 16; ++a)
        for (int b = a + 1; b < 16; ++b)
            for (int c = b + 1; c < 16; ++c) { t.a[k] = (short)a; t.b[k] = (short)b; t.c[k] = (short)c; ++k; }
    return t;
}
constexpr Tabs TT = make_tabs();

// cc is a compile-time constant under full unroll: folds to pure VALU on xv regs.
__device__ __forceinline__ float colval(const float (&xv)[16], int cc) {
    const int a = TT.a[cc], b = TT.b[cc], c = TT.c[cc];
    if (b < 0) return xv[a];
    if (c < 0) return fmaxf(xv[a] + xv[b] - 1.0f, 0.0f);
    return fmaxf(xv[a] + xv[b] + xv[c] - 2.0f, 0.0f);
}

__global__ __launch_bounds__(256, 2)
void luk_kernel(const float* __restrict__ x, float* __restrict__ out) {
    // 256 lane-rows * 7 quads * 16 B = 28 KB. Wave-private quadrants:
    // each wave transposes/stores only its own 64 rows -> no block barrier.
    __shared__ v4f lds[ROWS_PER_BLOCK * LDS_STRIDE_Q];

    const int t    = threadIdx.x;
    const int wave = t >> 6;
    const int lane = t & 63;
    const size_t row = (size_t)blockIdx.x * ROWS_PER_BLOCK + t;  // grid covers exactly

    // my row in registers (16 VGPRs)
    float xv[16];
    {
        const v4f* __restrict__ xr = reinterpret_cast<const v4f*>(x + row * 16);
        #pragma unroll
        for (int j = 0; j < 4; ++j) {
            const v4f v = xr[j];
            xv[4 * j + 0] = v.x; xv[4 * j + 1] = v.y;
            xv[4 * j + 2] = v.z; xv[4 * j + 3] = v.w;
        }
    }

    v4f* const myw   = &lds[t * LDS_STRIDE_Q];             // my write slots
    v4f* const rbase = &lds[(wave << 6) * LDS_STRIDE_Q];   // my wave's 64 rows
    float* const wout = out + ((size_t)blockIdx.x * ROWS_PER_BLOCK + (wave << 6)) * NCOLS;

    #pragma unroll
    for (int ch = 0; ch < NCHUNKS; ++ch) {
        const int c0 = ch * CHUNK_COLS;

        // compute 24 cols (6 quads) for my row, park in LDS (ds_write_b128,
        // lane stride 112 B -> optimal 8-phase, conflict-free)
        #pragma unroll
        for (int q = 0; q < CHUNK_QUADS; ++q) {
            v4f o;
            o.x = colval(xv, c0 + 4 * q + 0);
            o.y = colval(xv, c0 + 4 * q + 1);
            o.z = colval(xv, c0 + 4 * q + 2);
            o.w = colval(xv, c0 + 4 * q + 3);
            myw[q] = o;
        }
        __threadfence_block();   // lgkmcnt(0): writes visible wave-wide; vmcnt untouched

        // transposed read-back: wave stores its 64 rows' chunk coalesced
        #pragma unroll
        for (int v = 0; v < CHUNK_QUADS; ++v) {
            const unsigned g = (unsigned)(v * 64 + lane);   // 0..383
            const unsigned r = g / 6u;                      // row in wave (magic mul)
            const unsigned q = g - r * 6u;                  // quad in chunk
            const v4f val = rbase[r * LDS_STRIDE_Q + q];
            *reinterpret_cast<v4f*>(wout + (size_t)r * NCOLS + (c0 + 4 * q)) = val;
        }
        __threadfence_block();   // reads done before next chunk overwrites
    }
}

extern "C" void kernel_launch(void* const* d_in, const int* in_sizes, int n_in,
                              void* d_out, int out_size, void* d_ws, size_t ws_size,
                              hipStream_t stream) {
    const float* x = (const float*)d_in[0];
    float* out = (float*)d_out;
    const int nrows  = in_sizes[0] / 16;              // 131072
    const int blocks = nrows / ROWS_PER_BLOCK;        // 512, exact
    luk_kernel<<<blocks, 256, 0, stream>>>(x, out);
}